// Round 19
// baseline (181.600 us; speedup 1.0000x reference)
//
#include <hip/hip_runtime.h>
#include <hip/hip_bf16.h>
#include <stdint.h>

// ---------- types ----------
typedef _Float16 half2v __attribute__((ext_vector_type(2)));
typedef _Float16 half8v __attribute__((ext_vector_type(8)));
typedef uint32_t u32x4  __attribute__((ext_vector_type(4)));
typedef float    f32x4  __attribute__((ext_vector_type(4)));

__device__ __forceinline__ unsigned short f2h(float f) {
  _Float16 h = (_Float16)f;
  return __builtin_bit_cast(unsigned short, h);
}
__device__ __forceinline__ half2v bch2(uint32_t u) {
  return __builtin_bit_cast(half2v, u);
}
__device__ __forceinline__ uint32_t pkrtz_u32(float a, float b) {
  return __builtin_bit_cast(uint32_t, __builtin_amdgcn_cvt_pkrtz(a, b));
}

// Window-major qkv layout (channel 0 of head n, pixel (h,w)).
__device__ __forceinline__ int qkv_idx(int half, int b, int n, int h, int w) {
  int idx = half * 8388608 + (b * 8 + n) * 131072;
  idx += (half == 0) ? ((h >> 3) * 16384 + w * 256 + (h & 7) * 32)
                     : (h * 2048 + w * 32);
  return idx;
}

// async global->LDS, 16 bytes per lane. lbase = wave-uniform base.
#define GLOAD_LDS16(gsrc, lbase)                                          \
  __builtin_amdgcn_global_load_lds(                                       \
      (const __attribute__((address_space(1))) uint32_t*)(gsrc),          \
      (__attribute__((address_space(3))) uint32_t*)(lbase), 16, 0, 0)

// ---------- weight casts (x-cast is fused into gemm8p) ----------
__global__ __launch_bounds__(256) void cvt_weights(
    const float* __restrict__ wqkv, const float* __restrict__ wproj,
    const float* __restrict__ lh,   const float* __restrict__ lv,
    unsigned short* __restrict__ owqkv, unsigned short* __restrict__ owproj,
    unsigned short* __restrict__ owlep)
{
  int i = blockIdx.x * 256 + threadIdx.x;   // float4 index
  const float* src; unsigned short* dst; int off;
  if      (i < 196608) { src = wqkv;  dst = owqkv;        off = i; }
  else if (i < 262144) { src = wproj; dst = owproj;       off = i - 196608; }
  else if (i < 262720) { src = lh;    dst = owlep;        off = i - 262144; }
  else if (i < 263296) { src = lv;    dst = owlep + 2304; off = i - 262720; }
  else return;
  float4 f = reinterpret_cast<const float4*>(src)[off];
  ushort4 u;
  u.x = f2h(f.x); u.y = f2h(f.y); u.z = f2h(f.z); u.w = f2h(f.w);
  reinterpret_cast<ushort4*>(dst)[off] = u;
}

// ---------- GEMM1: persistent 8-phase 256^2, FUSED f32 A-cast ----------
// A is reg-staged from f32 x (T14): 8 float4 loads at p1 (odd tile) / p6
// (even tile); cvt_pkrtz + ds_write_b128 at p4/p8 after the counted vmcnt.
// LDS image is byte-identical to the gload_lds version (thread tid writes
// b*32768+u*8192+tid*16), so read side + swizzle unchanged.
// Waitcnt: p4 vmcnt(2) = drain B-odd-prev(4)+A-odd(8), keep 2 new B-even;
//          p8 vmcnt(4) = drain B-even(4)+A-even(8), keep 4 new B-odd;
// lgkmcnt(0) before each of those barriers makes A-writes visible.
// Grid 256 persistent (1 block/CU); bijective XCD swizzle; pass sweep of 3
// n-tiles with loads-early / write-after-vmcnt(0) boundary.
__global__ __launch_bounds__(512, 2) void gemm8p(
    const float* __restrict__ X,           // 32768 x 512 f32
    const unsigned short* __restrict__ Bm, // 1536 x 512 f16
    unsigned short* __restrict__ Cq)
{
  constexpr int K = 512;
  constexpr int NIT = 4;                    // K / 128
  __shared__ unsigned short As[2][256 * 64];   // 2 x 32KB
  __shared__ unsigned short Bs[2][256 * 64];   // 2 x 32KB
  const int tid  = threadIdx.x;
  const int cpx  = gridDim.x >> 3;                 // 32
  const int bid  = blockIdx.x;
  const int wgid = (bid & 7) * cpx + (bid >> 3);   // bijective (grid%8==0)
  const int mt   = wgid >> 1;        // 0..127
  const int nh   = wgid & 1;         // n-tile half: tiles nh*3 .. nh*3+2
  const int m0   = mt * 256;
  const int wave = tid >> 6, lane = tid & 63;
  const int wr  = wave >> 2;        // 0..1 (128 M-rows)
  const int wcn = wave & 3;         // 0..3 (64 N-cols)

  const int srow = tid >> 3;
  const int schk = ((tid & 7) ^ (srow & 7)) * 8;
  const size_t aSrc = (size_t)(m0 + srow) * K + schk;   // f32 elem offset
  size_t bSrc = (size_t)(nh * 768 + srow) * K + schk;   // pass0 n0 = nh*768
  char* ldsB = (char*)(&Bs[0][0]) + (tid & ~63) * 16;
  // A ds_write target: byte offset b*32768 + u*8192 + tid*16 within As
  unsigned short* const aw = &As[0][0] + tid * 8;

  float4 ar[4][2];   // reg-staged A: [unit][half-16B]

#define ALOAD(kt)                                                           \
  do {                                                                      \
    _Pragma("unroll")                                                       \
    for (int u = 0; u < 4; ++u) {                                           \
      ar[u][0] = *reinterpret_cast<const float4*>(X + aSrc + (size_t)u * 64 * K + (size_t)(kt) * 64);     \
      ar[u][1] = *reinterpret_cast<const float4*>(X + aSrc + (size_t)u * 64 * K + (size_t)(kt) * 64 + 4); \
    }                                                                       \
  } while (0)
#define AWRITE(b)                                                           \
  do {                                                                      \
    _Pragma("unroll")                                                       \
    for (int u = 0; u < 4; ++u) {                                           \
      u32x4 w;                                                              \
      w[0] = pkrtz_u32(ar[u][0].x, ar[u][0].y);                             \
      w[1] = pkrtz_u32(ar[u][0].z, ar[u][0].w);                             \
      w[2] = pkrtz_u32(ar[u][1].x, ar[u][1].y);                             \
      w[3] = pkrtz_u32(ar[u][1].z, ar[u][1].w);                             \
      *reinterpret_cast<u32x4*>(aw + (b) * 16384 + u * 4096) = w;           \
    }                                                                       \
  } while (0)
#define SB_U(b, kt, u, bS)                                                  \
  GLOAD_LDS16(Bm + (bS) + (size_t)(u) * 64 * K + (size_t)(kt) * 64,         \
              ldsB + (b) * 32768 + (u) * 8192)
#define BARS                                                                \
  __builtin_amdgcn_s_barrier();                                             \
  __builtin_amdgcn_sched_barrier(0)

  // initial prologue: A0 loads + B0(buf0) + B1(buf1) gloads
  ALOAD(0);
  SB_U(0, 0, 0, bSrc); SB_U(0, 0, 1, bSrc); SB_U(0, 0, 2, bSrc); SB_U(0, 0, 3, bSrc);
  SB_U(1, 1, 0, bSrc); SB_U(1, 1, 1, bSrc); SB_U(1, 1, 2, bSrc); SB_U(1, 1, 3, bSrc);
  asm volatile("s_waitcnt vmcnt(8)" ::: "memory");   // A0 regs landed
  AWRITE(0);
  asm volatile("s_waitcnt vmcnt(4) lgkmcnt(0)" ::: "memory"); // B0 in LDS, A0 written
  BARS;

  const int lr  = lane & 15;
  const int kg  = lane >> 4;
  const int ck0 = kg ^ (lr & 7);            // k-step0 slot; k-step1 = ck0^4

#define LD_AF(buf, mg, ks)                                                  \
  do {                                                                      \
    const unsigned short* ap = &As[buf][0] +                                \
        (wr * 128 + (mg) * 64 + lr) * 64 + (((ks) ? (ck0 ^ 4) : ck0)) * 8;  \
    af[0] = *(const half8v*)(ap);                                           \
    af[1] = *(const half8v*)(ap + 1024);                                    \
    af[2] = *(const half8v*)(ap + 2048);                                    \
    af[3] = *(const half8v*)(ap + 3072);                                    \
  } while (0)
#define LD_BF(buf, ks)                                                      \
  do {                                                                      \
    const unsigned short* bp = &Bs[buf][0] +                                \
        (wcn * 64 + lr) * 64 + (((ks) ? (ck0 ^ 4) : ck0)) * 8;              \
    bf[0] = *(const half8v*)(bp);                                           \
    bf[1] = *(const half8v*)(bp + 1024);                                    \
    bf[2] = *(const half8v*)(bp + 2048);                                    \
    bf[3] = *(const half8v*)(bp + 3072);                                    \
  } while (0)
#define MROW(mg, i)                                                         \
  acc[(mg)*4+(i)][0] = __builtin_amdgcn_mfma_f32_16x16x32_f16(bf[0], af[i], acc[(mg)*4+(i)][0], 0, 0, 0); \
  acc[(mg)*4+(i)][1] = __builtin_amdgcn_mfma_f32_16x16x32_f16(bf[1], af[i], acc[(mg)*4+(i)][1], 0, 0, 0); \
  acc[(mg)*4+(i)][2] = __builtin_amdgcn_mfma_f32_16x16x32_f16(bf[2], af[i], acc[(mg)*4+(i)][2], 0, 0, 0); \
  acc[(mg)*4+(i)][3] = __builtin_amdgcn_mfma_f32_16x16x32_f16(bf[3], af[i], acc[(mg)*4+(i)][3], 0, 0, 0);
#define MFMA16(mg)                                                          \
  do {                                                                      \
    __builtin_amdgcn_s_setprio(1);                                          \
    MROW(mg, 0); MROW(mg, 1); MROW(mg, 2); MROW(mg, 3);                     \
    __builtin_amdgcn_s_setprio(0);                                          \
  } while (0)

  f32x4 acc[8][4];
  const f32x4 zero = {0.f, 0.f, 0.f, 0.f};

  #pragma unroll 1
  for (int pass = 0; pass < 3; ++pass) {
    const int n0 = (nh * 3 + pass) * 256;
    #pragma unroll
    for (int i = 0; i < 8; ++i)
      #pragma unroll
      for (int j = 0; j < 4; ++j) acc[i][j] = zero;

    for (int it2 = 0; it2 < NIT; ++it2) {
      const bool more = (it2 + 1 < NIT);
      const int keven = 2 * it2;
      half8v af[4], bf[4];
      // p1: reads buf0; issue A(odd) f32 loads (8 vmem)
      LD_BF(0, 0); LD_AF(0, 0, 0);
      ALOAD(keven + 1);
      BARS;
      MFMA16(0);
      BARS;
      // p2
      LD_AF(0, 1, 0);
      BARS;
      MFMA16(1);
      BARS;
      // p3
      LD_BF(0, 1); LD_AF(0, 0, 1);
      BARS;
      MFMA16(0);
      BARS;
      // p4: stage B(next even)->buf0 u0,u1; vmcnt(2) drains B-odd-prev+A-odd;
      // then write A(odd) into buf1 (read starting p5).
      LD_AF(0, 1, 1);
      if (more) {
        SB_U(0, keven + 2, 0, bSrc); SB_U(0, keven + 2, 1, bSrc);
        asm volatile("s_waitcnt vmcnt(2)" ::: "memory");
      } else {
        asm volatile("s_waitcnt vmcnt(0)" ::: "memory");
      }
      AWRITE(1);
      asm volatile("s_waitcnt lgkmcnt(0)" ::: "memory");
      BARS;
      MFMA16(1);
      BARS;
      // p5: stage B(next even)->buf0 u2,u3
      LD_BF(1, 0); LD_AF(1, 0, 0);
      if (more) { SB_U(0, keven + 2, 2, bSrc); SB_U(0, keven + 2, 3, bSrc); }
      BARS;
      MFMA16(0);
      BARS;
      // p6: issue A(next even) f32 loads
      LD_AF(1, 1, 0);
      if (more) ALOAD(keven + 2);
      BARS;
      MFMA16(1);
      BARS;
      // p7
      LD_BF(1, 1); LD_AF(1, 0, 1);
      BARS;
      MFMA16(0);
      BARS;
      // p8: stage B(next odd)->buf1 u0..u3; vmcnt(4) drains B-even+A-even;
      // then write A(even) into buf0 (read next iter p1).
      LD_AF(1, 1, 1);
      if (more) {
        SB_U(1, keven + 3, 0, bSrc); SB_U(1, keven + 3, 1, bSrc);
        SB_U(1, keven + 3, 2, bSrc); SB_U(1, keven + 3, 3, bSrc);
        asm volatile("s_waitcnt vmcnt(4)" ::: "memory");
        AWRITE(0);
        asm volatile("s_waitcnt lgkmcnt(0)" ::: "memory");
      }
      BARS;
      MFMA16(1);
      BARS;
    }
    // pass end: 0 VMEM outstanding; all waves past both buffers.

    if (pass < 2) {
      // next pass prologue loads BEFORE epilogue stores (latency hides)
      const size_t bSrcN = bSrc + (size_t)256 * K;
      ALOAD(0);
      SB_U(0, 0, 0, bSrcN); SB_U(0, 0, 1, bSrcN); SB_U(0, 0, 2, bSrcN); SB_U(0, 0, 3, bSrcN);
      SB_U(1, 1, 0, bSrcN); SB_U(1, 1, 1, bSrcN); SB_U(1, 1, 2, bSrcN); SB_U(1, 1, 3, bSrcN);
      bSrc = bSrcN;
    }

    // epilogue: scatter to window-major qkv regions
    {
      const int cr = (lane >> 4) * 4;
      const int cc = lane & 15;
      const int mb   = m0 + wr * 128;
      const int btok = mb >> 12;
      const int hr0  = (mb >> 6) & 63;
      #pragma unroll
      for (int j = 0; j < 4; ++j) {
        const int nb    = n0 + wcn * 64 + j * 16 + cr;
        const int tq    = nb >> 9;
        const int halfc = (nb >> 8) & 1;
        const int nn    = (nb & 255) >> 5;
        const int ch4   = nb & 31;
        const int headbase = tq * 16777216 + halfc * 8388608 +
                             (btok * 8 + nn) * 131072 + ch4;
        #pragma unroll
        for (int i = 0; i < 8; ++i) {
          const int hrow = hr0 + (i >> 2);
          const int wpix = (i & 3) * 16 + cc;
          const int off = halfc ? (hrow * 2048 + wpix * 32)
                                : ((hrow >> 3) * 16384 + wpix * 256 + (hrow & 7) * 32);
          uint2 r;
          r.x = pkrtz_u32(acc[i][j][0], acc[i][j][1]);
          r.y = pkrtz_u32(acc[i][j][2], acc[i][j][3]);
          *reinterpret_cast<uint2*>(Cq + headbase + off) = r;
        }
      }
    }

    if (pass < 2) {
      asm volatile("s_waitcnt vmcnt(0)" ::: "memory");  // loads+stores done
      AWRITE(0);                                        // A0' into buf0
      asm volatile("s_waitcnt lgkmcnt(0)" ::: "memory");
      BARS;                                             // all waves see tiles
    }
  }
#undef ALOAD
#undef AWRITE
#undef SB_U
#undef LD_AF
#undef LD_BF
#undef MROW
#undef MFMA16
#undef BARS
}

// ---------- GEMM2: out = attn_out(f16) @ w_proj(f16)^T + bias -> f32 ----------
// R9-proven 128x128 2-phase, gload_lds, counted vmcnt(4); grid 1024 = 4/CU TLP.
__global__ __launch_bounds__(256) void gemm_proj(
    const unsigned short* __restrict__ A,
    const unsigned short* __restrict__ B,
    float* __restrict__ Cf,
    const float* __restrict__ bias)
{
  constexpr int K = 512, N = 512;
  __shared__ unsigned short As[2][128 * 32];
  __shared__ unsigned short Bs[2][128 * 32];
  const int tid  = threadIdx.x;
  const int gn   = N >> 7;                 // 4
  const int cpx  = gridDim.x >> 3;
  const int bid  = blockIdx.x;
  const int wgid = (bid & 7) * cpx + (bid >> 3);
  const int m0   = (wgid / gn) * 128;
  const int n0   = (wgid % gn) * 128;
  const int wave = tid >> 6, lane = tid & 63;
  const int wr = wave >> 1, wc = wave & 1;
  const int sr = tid >> 2;
  const int sc = ((tid & 3) ^ ((tid >> 3) & 3)) * 8;
  const size_t aBase0 = (size_t)(m0 + sr) * K + sc;
  const size_t aBase1 = (size_t)(m0 + 64 + sr) * K + sc;
  const size_t bBase0 = (size_t)(n0 + sr) * K + sc;
  const size_t bBase1 = (size_t)(n0 + 64 + sr) * K + sc;
  char* ldsA = (char*)(&As[0][0]) + (tid & ~63) * 16;
  char* ldsB = (char*)(&Bs[0][0]) + (tid & ~63) * 16;

#define STAGE_P(bsel, kofs)                                        \
  do {                                                             \
    GLOAD_LDS16(A + aBase0 + (kofs), ldsA + (bsel) * 8192);        \
    GLOAD_LDS16(A + aBase1 + (kofs), ldsA + (bsel) * 8192 + 4096); \
    GLOAD_LDS16(B + bBase0 + (kofs), ldsB + (bsel) * 8192);        \
    GLOAD_LDS16(B + bBase1 + (kofs), ldsB + (bsel) * 8192 + 4096); \
  } while (0)

  STAGE_P(0, 0);

  f32x4 acc[4][4];
  const f32x4 zero = {0.f, 0.f, 0.f, 0.f};
  #pragma unroll
  for (int i = 0; i < 4; ++i)
    #pragma unroll
    for (int j = 0; j < 4; ++j) acc[i][j] = zero;

  const int lr   = lane & 15;
  const int slot = (lane >> 4) ^ ((lr >> 1) & 3);

  auto compute = [&](const unsigned short* Asb, const unsigned short* Bsb) {
    half8v af[4], bfr[4];
    #pragma unroll
    for (int i = 0; i < 4; ++i)
      af[i] = *reinterpret_cast<const half8v*>(Asb + (wr * 64 + i * 16 + lr) * 32 + slot * 8);
    #pragma unroll
    for (int j = 0; j < 4; ++j)
      bfr[j] = *reinterpret_cast<const half8v*>(Bsb + (wc * 64 + j * 16 + lr) * 32 + slot * 8);
    __builtin_amdgcn_s_setprio(1);
    #pragma unroll
    for (int i = 0; i < 4; ++i)
      #pragma unroll
      for (int j = 0; j < 4; ++j)
        acc[i][j] = __builtin_amdgcn_mfma_f32_16x16x32_f16(bfr[j], af[i], acc[i][j], 0, 0, 0);
    __builtin_amdgcn_s_setprio(0);
  };

  const int nt = K >> 5;
  for (int t = 0; t < nt - 1; ++t) {
    STAGE_P((t + 1) & 1, (t + 1) * 32);
    asm volatile("s_waitcnt vmcnt(4)" ::: "memory");
    __builtin_amdgcn_s_barrier();
    __builtin_amdgcn_sched_barrier(0);
    compute(&As[t & 1][0], &Bs[t & 1][0]);
    __builtin_amdgcn_s_barrier();
    __builtin_amdgcn_sched_barrier(0);
  }
  asm volatile("s_waitcnt vmcnt(0)" ::: "memory");
  __builtin_amdgcn_s_barrier();
  __builtin_amdgcn_sched_barrier(0);
  compute(&As[(nt - 1) & 1][0], &Bs[(nt - 1) & 1][0]);
#undef STAGE_P

  const int cr = (lane >> 4) * 4;
  const int cc = lane & 15;
  #pragma unroll
  for (int j = 0; j < 4; ++j) {
    const int n = n0 + wc * 64 + j * 16 + cr;
    const float4 b4 = *reinterpret_cast<const float4*>(bias + n);
    #pragma unroll
    for (int i = 0; i < 4; ++i) {
      const int m = m0 + wr * 64 + i * 16 + cc;
      float4 r;
      r.x = acc[i][j][0] + b4.x;
      r.y = acc[i][j][1] + b4.y;
      r.z = acc[i][j][2] + b4.z;
      r.w = acc[i][j][3] + b4.w;
      *reinterpret_cast<float4*>(Cf + (size_t)m * N + n) = r;
    }
  }
}

// ---------- stripe attention + LePE, TWO windows per wave ----------
__global__ __launch_bounds__(256) void attn_lepe(
    const unsigned short* __restrict__ qkvp,
    const unsigned short* __restrict__ wlep,
    unsigned short* __restrict__ outp)
{
  const int gw   = (int)((blockIdx.x * 256 + threadIdx.x) >> 6);  // pair index
  const int lane = threadIdx.x & 63;
  const int half = gw >> 14;
  const int id   = gw & 16383;
  const int b    = id >> 11;
  const int n    = (id >> 8) & 7;
  int h0, w0;
  if (half == 0) { h0 = ((id >> 5) & 7) * 8; w0 = (id & 31) * 2; }
  else           { h0 = ((id >> 3) & 31) * 2; w0 = (id & 7) * 8; }
  const int baseA = qkv_idx(half, b, n, h0, w0);
  const int dWin  = (half == 0) ? 256 : 2048;
  const int baseB = baseA + dWin;

  // ---- QK^T for both windows: lane = (qr, kr) ----
  const int qr = lane >> 3, kr = lane & 7;
  const unsigned short* qA = qkvp + baseA + qr * 32;
  const unsigned short* kA = qkvp + 16777216 + baseA + kr * 32;
  float sA = 0.f, sB = 0.f;
  #pragma unroll
  for (int c = 0; c < 4; ++c) {
    const u32x4 qa = *reinterpret_cast<const u32x4*>(qA + c * 8);
    const u32x4 ka = *reinterpret_cast<const u32x4*>(kA + c * 8);
    const u32x4 qb = *reinterpret_cast<const u32x4*>(qA + dWin + c * 8);
    const u32x4 kb = *reinterpret_cast<const u32x4*>(kA + dWin + c * 8);
    #pragma unroll
    for (int e = 0; e < 4; ++e) {
      sA = __builtin_amdgcn_fdot2(bch2(qa[e]), bch2(ka[e]), sA, false);
      sB = __builtin_amdgcn_fdot2(bch2(qb[e]), bch2(kb[e]), sB, false);
    }
  }
  const float scl = 0.17677669529663687f;
  const float pA = __expf(sA * scl);
  const float pB = __expf(sB * scl);
  float denA = pA, denB = pB;
  denA += __shfl_xor(denA, 1); denA += __shfl_xor(denA, 2); denA += __shfl_xor(denA, 4);
  denB += __shfl_xor(denB, 1); denB += __shfl_xor(denB, 2); denB += __shfl_xor(denB, 4);
  const float aAv = pA * __builtin_amdgcn_rcpf(denA);
  const float aBv = pB * __builtin_amdgcn_rcpf(denB);
  const uint32_t adu = pkrtz_u32(aAv, aBv);   // lo = winA, hi = winB

  // ---- PV: lane = (qr2, win, dgrp); 16B vectors over 8 channels ----
  const int dgrp = lane & 3;
  const int win  = (lane >> 2) & 1;
  const int qr2  = lane >> 3;
  const int d0   = dgrp * 8;
  const int mybase = win ? baseB : baseA;
  const unsigned short* vwin = qkvp + 33554432 + mybase;

  half2v o01 = {0,0}, o23 = {0,0}, o45 = {0,0}, o67 = {0,0};
  #pragma unroll
  for (int k = 0; k < 8; ++k) {
    const uint32_t pairw = (uint32_t)__shfl((int)adu, qr2 * 8 + k);
    const half2v ph = bch2(pairw);
    const _Float16 av = win ? ph.y : ph.x;
    const half2v ak2 = {av, av};
    const u32x4 vv = *reinterpret_cast<const u32x4*>(vwin + k * 32 + d0);
    o01 += ak2 * bch2(vv[0]);
    o23 += ak2 * bch2(vv[1]);
    o45 += ak2 * bch2(vv[2]);
    o67 += ak2 * bch2(vv[3]);
  }

  // ---- LePE: depthwise 3x3 on v (zero-pad SAME) at this lane's pixel ----
  const int hq = (half == 0) ? (h0 + qr2) : (h0 + win);
  const int wq = (half == 0) ? (w0 + win) : (w0 + qr2);
  const unsigned short* vplane = qkvp + 33554432;
  const unsigned short* wl = wlep + half * 2304 + n * 32 + d0;
  half2v l01 = {0,0}, l23 = {0,0}, l45 = {0,0}, l67 = {0,0};
  #pragma unroll
  for (int dy = -1; dy <= 1; ++dy) {
    #pragma unroll
    for (int dx = -1; dx <= 1; ++dx) {
      const int hh = hq + dy, ww = wq + dx;
      u32x4 vv = {0u, 0u, 0u, 0u};
      if ((unsigned)hh < 64u && (unsigned)ww < 64u)
        vv = *reinterpret_cast<const u32x4*>(vplane + qkv_idx(half, b, n, hh, ww) + d0);
      const u32x4 wt = *reinterpret_cast<const u32x4*>(wl + ((dy + 1) * 3 + dx + 1) * 256);
      l01 += bch2(wt[0]) * bch2(vv[0]);
      l23 += bch2(wt[1]) * bch2(vv[1]);
      l45 += bch2(wt[2]) * bch2(vv[2]);
      l67 += bch2(wt[3]) * bch2(vv[3]);
    }
  }

  // ---- store token-major for GEMM2 (16B per lane) ----
  const int m = b * 4096 + hq * 64 + wq;
  const int chan0 = half * 256 + n * 32;
  u32x4 r;
  r[0] = __builtin_bit_cast(uint32_t, (half2v)(o01 + l01));
  r[1] = __builtin_bit_cast(uint32_t, (half2v)(o23 + l23));
  r[2] = __builtin_bit_cast(uint32_t, (half2v)(o45 + l45));
  r[3] = __builtin_bit_cast(uint32_t, (half2v)(o67 + l67));
  *reinterpret_cast<u32x4*>(outp + (size_t)m * 512 + chan0 + d0) = r;
}

// ---------- launch ----------
extern "C" void kernel_launch(void* const* d_in, const int* in_sizes, int n_in,
                              void* d_out, int out_size, void* d_ws, size_t ws_size,
                              hipStream_t stream) {
  const float* x      = (const float*)d_in[0];   // (8, 4096, 512)
  const float* w_qkv  = (const float*)d_in[1];   // (1536, 512)
  const float* w_proj = (const float*)d_in[2];   // (512, 512)
  const float* b_proj = (const float*)d_in[3];   // (512,)
  const float* lepe_h = (const float*)d_in[4];   // (3,3,1,256)
  const float* lepe_v = (const float*)d_in[5];   // (3,3,1,256)
  float* out = (float*)d_out;                    // (8, 4096, 512) f32

  char* ws = (char*)d_ws;
  unsigned short* qkv_p   = (unsigned short*)ws;                 // 96MB: q|k|v window-major
  unsigned short* ah      = (unsigned short*)(ws + 100663296);   // 32MB: attn_out f16
  unsigned short* wqkv_h  = (unsigned short*)(ws + 134217728);   // 1536*512 f16
  unsigned short* wproj_h = (unsigned short*)(ws + 135790592);   // 512*512 f16
  unsigned short* wlep_h  = (unsigned short*)(ws + 136314880);   // 2*9*256 f16

  // weight casts only (x-cast fused into gemm8p)
  cvt_weights<<<1029, 256, 0, stream>>>(w_qkv, w_proj, lepe_h, lepe_v,
                                        wqkv_h, wproj_h, wlep_h);

  // qkv = x @ w_qkv^T -> window-major f16 (persistent 8-phase, fused A-cast)
  gemm8p<<<256, 512, 0, stream>>>(x, wqkv_h, qkv_p);

  // stripe attention + LePE -> attn_out token-major
  attn_lepe<<<8192, 256, 0, stream>>>(qkv_p, wlep_h, ah);

  // out = attn_out @ w_proj^T + b_proj -> f32 (128^2 2-phase; grid 1024)
  gemm_proj<<<1024, 256, 0, stream>>>(ah, wproj_h, out, b_proj);
}

// Round 20
// 169.608 us; speedup vs baseline: 1.0707x; 1.0707x over previous
//
#include <hip/hip_runtime.h>
#include <hip/hip_bf16.h>
#include <stdint.h>

// ---------- types ----------
typedef _Float16 half2v __attribute__((ext_vector_type(2)));
typedef _Float16 half8v __attribute__((ext_vector_type(8)));
typedef uint32_t u32x4  __attribute__((ext_vector_type(4)));
typedef float    f32x4  __attribute__((ext_vector_type(4)));

__device__ __forceinline__ unsigned short f2h(float f) {
  _Float16 h = (_Float16)f;
  return __builtin_bit_cast(unsigned short, h);
}
__device__ __forceinline__ half2v bch2(uint32_t u) {
  return __builtin_bit_cast(half2v, u);
}
__device__ __forceinline__ uint32_t pkrtz_u32(float a, float b) {
  return __builtin_bit_cast(uint32_t, __builtin_amdgcn_cvt_pkrtz(a, b));
}

// Window-major qkv layout (channel 0 of head n, pixel (h,w)).
__device__ __forceinline__ int qkv_idx(int half, int b, int n, int h, int w) {
  int idx = half * 8388608 + (b * 8 + n) * 131072;
  idx += (half == 0) ? ((h >> 3) * 16384 + w * 256 + (h & 7) * 32)
                     : (h * 2048 + w * 32);
  return idx;
}

// async global->LDS, 16 bytes per lane. lbase = wave-uniform base.
#define GLOAD_LDS16(gsrc, lbase)                                          \
  __builtin_amdgcn_global_load_lds(                                       \
      (const __attribute__((address_space(1))) uint32_t*)(gsrc),          \
      (__attribute__((address_space(3))) uint32_t*)(lbase), 16, 0, 0)

// ---------- ONE cast kernel: x (f32->f16) + all weights ----------
__global__ __launch_bounds__(256) void cvt_all(
    const float* __restrict__ x,
    const float* __restrict__ wqkv, const float* __restrict__ wproj,
    const float* __restrict__ lh,   const float* __restrict__ lv,
    unsigned short* __restrict__ ox,
    unsigned short* __restrict__ owqkv, unsigned short* __restrict__ owproj,
    unsigned short* __restrict__ owlep)
{
  int i = blockIdx.x * 256 + threadIdx.x;   // float4 index
  const float* src; unsigned short* dst; int off;
  if (i < 4194304)      { src = x;     dst = ox;           off = i; }
  else if ((i -= 4194304) < 196608) { src = wqkv;  dst = owqkv;  off = i; }
  else if ((i -= 196608) < 65536)   { src = wproj; dst = owproj; off = i; }
  else if ((i -= 65536) < 576)      { src = lh;    dst = owlep;  off = i; }
  else if ((i -= 576) < 576)        { src = lv;    dst = owlep + 2304; off = i; }
  else return;
  float4 f = reinterpret_cast<const float4*>(src)[off];
  ushort4 u;
  u.x = f2h(f.x); u.y = f2h(f.y); u.z = f2h(f.z); u.w = f2h(f.w);
  reinterpret_cast<ushort4*>(dst)[off] = u;
}

// ---------- GEMM1: persistent 8-phase 256^2 f16 (R18 best measured) ----------
// Grid 256 = exactly 1 block/CU, zero dispatch tail. Each block owns m-tile
// mt = wgid>>1 and sweeps 3 n-tiles (nh = wgid&1 selects which half of the 6).
// K-loop = verified 8-phase body (spread staging, counted vmcnt).
// Pass boundary: issue next pass's 12-load prologue BEFORE the epilogue's
// 32 scattered stores (load latency hides under store issue), then
// vmcnt(0)+barrier -> next K-loop enters with 0 outstanding.
__global__ __launch_bounds__(512, 2) void gemm8p(
    const unsigned short* __restrict__ A,
    const unsigned short* __restrict__ Bm,
    unsigned short* __restrict__ Cq)
{
  constexpr int K = 512;
  constexpr int NIT = 4;                    // K / 128
  __shared__ unsigned short As[2][256 * 64];   // 2 x 32KB
  __shared__ unsigned short Bs[2][256 * 64];   // 2 x 32KB
  const int tid  = threadIdx.x;
  const int cpx  = gridDim.x >> 3;                 // 32
  const int bid  = blockIdx.x;
  const int wgid = (bid & 7) * cpx + (bid >> 3);   // bijective (grid%8==0)
  const int mt   = wgid >> 1;        // 0..127
  const int nh   = wgid & 1;         // n-tile half: tiles nh*3 .. nh*3+2
  const int m0   = mt * 256;
  const int wave = tid >> 6, lane = tid & 63;
  const int wr  = wave >> 2;        // 0..1 (128 M-rows)
  const int wcn = wave & 3;         // 0..3 (64 N-cols)

  const int srow = tid >> 3;
  const int schk = ((tid & 7) ^ (srow & 7)) * 8;
  const size_t aSrc = (size_t)(m0 + srow) * K + schk;
  size_t bSrc = (size_t)(nh * 768 + srow) * K + schk;   // pass0 n0 = nh*768
  char* ldsA = (char*)(&As[0][0]) + (tid & ~63) * 16;
  char* ldsB = (char*)(&Bs[0][0]) + (tid & ~63) * 16;

#define SA_U(b, kt, u)                                                      \
  GLOAD_LDS16(A + aSrc + (size_t)(u) * 64 * K + (size_t)(kt) * 64,          \
              ldsA + (b) * 32768 + (u) * 8192)
#define SB_U(b, kt, u, bS)                                                  \
  GLOAD_LDS16(Bm + (bS) + (size_t)(u) * 64 * K + (size_t)(kt) * 64,         \
              ldsB + (b) * 32768 + (u) * 8192)
#define BARS                                                                \
  __builtin_amdgcn_s_barrier();                                             \
  __builtin_amdgcn_sched_barrier(0)

  // initial prologue: tile0 (buf0) full + tile1 B (buf1) in flight
  SA_U(0, 0, 0); SA_U(0, 0, 1); SA_U(0, 0, 2); SA_U(0, 0, 3);
  SB_U(0, 0, 0, bSrc); SB_U(0, 0, 1, bSrc); SB_U(0, 0, 2, bSrc); SB_U(0, 0, 3, bSrc);
  SB_U(1, 1, 0, bSrc); SB_U(1, 1, 1, bSrc); SB_U(1, 1, 2, bSrc); SB_U(1, 1, 3, bSrc);
  asm volatile("s_waitcnt vmcnt(4)" ::: "memory");
  BARS;

  const int lr  = lane & 15;
  const int kg  = lane >> 4;
  const int ck0 = kg ^ (lr & 7);            // k-step0 slot; k-step1 = ck0^4

#define LD_AF(buf, mg, ks)                                                  \
  do {                                                                      \
    const unsigned short* ap = &As[buf][0] +                                \
        (wr * 128 + (mg) * 64 + lr) * 64 + (((ks) ? (ck0 ^ 4) : ck0)) * 8;  \
    af[0] = *(const half8v*)(ap);                                           \
    af[1] = *(const half8v*)(ap + 1024);                                    \
    af[2] = *(const half8v*)(ap + 2048);                                    \
    af[3] = *(const half8v*)(ap + 3072);                                    \
  } while (0)
#define LD_BF(buf, ks)                                                      \
  do {                                                                      \
    const unsigned short* bp = &Bs[buf][0] +                                \
        (wcn * 64 + lr) * 64 + (((ks) ? (ck0 ^ 4) : ck0)) * 8;              \
    bf[0] = *(const half8v*)(bp);                                           \
    bf[1] = *(const half8v*)(bp + 1024);                                    \
    bf[2] = *(const half8v*)(bp + 2048);                                    \
    bf[3] = *(const half8v*)(bp + 3072);                                    \
  } while (0)
#define MROW(mg, i)                                                         \
  acc[(mg)*4+(i)][0] = __builtin_amdgcn_mfma_f32_16x16x32_f16(bf[0], af[i], acc[(mg)*4+(i)][0], 0, 0, 0); \
  acc[(mg)*4+(i)][1] = __builtin_amdgcn_mfma_f32_16x16x32_f16(bf[1], af[i], acc[(mg)*4+(i)][1], 0, 0, 0); \
  acc[(mg)*4+(i)][2] = __builtin_amdgcn_mfma_f32_16x16x32_f16(bf[2], af[i], acc[(mg)*4+(i)][2], 0, 0, 0); \
  acc[(mg)*4+(i)][3] = __builtin_amdgcn_mfma_f32_16x16x32_f16(bf[3], af[i], acc[(mg)*4+(i)][3], 0, 0, 0);
#define MFMA16(mg)                                                          \
  do {                                                                      \
    __builtin_amdgcn_s_setprio(1);                                          \
    MROW(mg, 0); MROW(mg, 1); MROW(mg, 2); MROW(mg, 3);                     \
    __builtin_amdgcn_s_setprio(0);                                          \
  } while (0)

  f32x4 acc[8][4];
  const f32x4 zero = {0.f, 0.f, 0.f, 0.f};

  #pragma unroll 1
  for (int pass = 0; pass < 3; ++pass) {
    const int n0 = (nh * 3 + pass) * 256;
    #pragma unroll
    for (int i = 0; i < 8; ++i)
      #pragma unroll
      for (int j = 0; j < 4; ++j) acc[i][j] = zero;

    for (int it2 = 0; it2 < NIT; ++it2) {
      const bool more = (it2 + 1 < NIT);
      const int keven = 2 * it2;
      half8v af[4], bf[4];
      // p1: reads buf0; stage A(odd)->buf1 units 0,1
      LD_BF(0, 0); LD_AF(0, 0, 0);
      SA_U(1, keven + 1, 0); SA_U(1, keven + 1, 1);
      BARS;
      MFMA16(0);
      BARS;
      // p2: stage A(odd)->buf1 units 2,3
      LD_AF(0, 1, 0);
      SA_U(1, keven + 1, 2); SA_U(1, keven + 1, 3);
      BARS;
      MFMA16(1);
      BARS;
      // p3
      LD_BF(0, 1); LD_AF(0, 0, 1);
      BARS;
      MFMA16(0);
      BARS;
      // p4: stage B(next even)->buf0 units 0,1; vmcnt(2)
      LD_AF(0, 1, 1);
      if (more) {
        SB_U(0, keven + 2, 0, bSrc); SB_U(0, keven + 2, 1, bSrc);
        asm volatile("s_waitcnt vmcnt(2)" ::: "memory");
      } else {
        asm volatile("s_waitcnt vmcnt(0)" ::: "memory");
      }
      BARS;
      MFMA16(1);
      BARS;
      // p5: stage B(next even)->buf0 units 2,3
      LD_BF(1, 0); LD_AF(1, 0, 0);
      if (more) { SB_U(0, keven + 2, 2, bSrc); SB_U(0, keven + 2, 3, bSrc); }
      BARS;
      MFMA16(0);
      BARS;
      // p6: stage A(next even)->buf0 units 0,1
      LD_AF(1, 1, 0);
      if (more) { SA_U(0, keven + 2, 0); SA_U(0, keven + 2, 1); }
      BARS;
      MFMA16(1);
      BARS;
      // p7: stage A(next even)->buf0 units 2,3
      LD_BF(1, 1); LD_AF(1, 0, 1);
      if (more) { SA_U(0, keven + 2, 2); SA_U(0, keven + 2, 3); }
      BARS;
      MFMA16(0);
      BARS;
      // p8: stage B(next odd)->buf1 all 4; vmcnt(4)
      LD_AF(1, 1, 1);
      if (more) {
        SB_U(1, keven + 3, 0, bSrc); SB_U(1, keven + 3, 1, bSrc);
        SB_U(1, keven + 3, 2, bSrc); SB_U(1, keven + 3, 3, bSrc);
        asm volatile("s_waitcnt vmcnt(4)" ::: "memory");
      }
      BARS;
      MFMA16(1);
      BARS;
    }
    // pass end: 0 VMEM outstanding; all waves past reading both buffers.

    if (pass < 2) {
      // prologue for next pass BEFORE epilogue: loads hide under store issue
      const size_t bSrcN = bSrc + (size_t)256 * K;
      SA_U(0, 0, 0); SA_U(0, 0, 1); SA_U(0, 0, 2); SA_U(0, 0, 3);
      SB_U(0, 0, 0, bSrcN); SB_U(0, 0, 1, bSrcN); SB_U(0, 0, 2, bSrcN); SB_U(0, 0, 3, bSrcN);
      SB_U(1, 1, 0, bSrcN); SB_U(1, 1, 1, bSrcN); SB_U(1, 1, 2, bSrcN); SB_U(1, 1, 3, bSrcN);
      bSrc = bSrcN;
    }

    // epilogue: scatter to window-major qkv regions
    {
      const int cr = (lane >> 4) * 4;
      const int cc = lane & 15;
      const int mb   = m0 + wr * 128;
      const int btok = mb >> 12;
      const int hr0  = (mb >> 6) & 63;
      #pragma unroll
      for (int j = 0; j < 4; ++j) {
        const int nb    = n0 + wcn * 64 + j * 16 + cr;
        const int tq    = nb >> 9;
        const int halfc = (nb >> 8) & 1;
        const int nn    = (nb & 255) >> 5;
        const int ch4   = nb & 31;
        const int headbase = tq * 16777216 + halfc * 8388608 +
                             (btok * 8 + nn) * 131072 + ch4;
        #pragma unroll
        for (int i = 0; i < 8; ++i) {
          const int hrow = hr0 + (i >> 2);
          const int wpix = (i & 3) * 16 + cc;
          const int off = halfc ? (hrow * 2048 + wpix * 32)
                                : ((hrow >> 3) * 16384 + wpix * 256 + (hrow & 7) * 32);
          uint2 r;
          r.x = pkrtz_u32(acc[i][j][0], acc[i][j][1]);
          r.y = pkrtz_u32(acc[i][j][2], acc[i][j][3]);
          *reinterpret_cast<uint2*>(Cq + headbase + off) = r;
        }
      }
    }

    if (pass < 2) {
      asm volatile("s_waitcnt vmcnt(0)" ::: "memory");  // prologue landed
      BARS;                                             // all waves see tiles
    }
  }
#undef SA_U
#undef SB_U
#undef LD_AF
#undef LD_BF
#undef MROW
#undef MFMA16
#undef BARS
}

// ---------- GEMM2: out = attn_out(f16) @ w_proj(f16)^T + bias -> f32 ----------
// R9-proven 128x128 2-phase, gload_lds, counted vmcnt(4); grid 1024 = 4/CU TLP.
__global__ __launch_bounds__(256) void gemm_proj(
    const unsigned short* __restrict__ A,
    const unsigned short* __restrict__ B,
    float* __restrict__ Cf,
    const float* __restrict__ bias)
{
  constexpr int K = 512, N = 512;
  __shared__ unsigned short As[2][128 * 32];
  __shared__ unsigned short Bs[2][128 * 32];
  const int tid  = threadIdx.x;
  const int gn   = N >> 7;                 // 4
  const int cpx  = gridDim.x >> 3;
  const int bid  = blockIdx.x;
  const int wgid = (bid & 7) * cpx + (bid >> 3);
  const int m0   = (wgid / gn) * 128;
  const int n0   = (wgid % gn) * 128;
  const int wave = tid >> 6, lane = tid & 63;
  const int wr = wave >> 1, wc = wave & 1;
  const int sr = tid >> 2;
  const int sc = ((tid & 3) ^ ((tid >> 3) & 3)) * 8;
  const size_t aBase0 = (size_t)(m0 + sr) * K + sc;
  const size_t aBase1 = (size_t)(m0 + 64 + sr) * K + sc;
  const size_t bBase0 = (size_t)(n0 + sr) * K + sc;
  const size_t bBase1 = (size_t)(n0 + 64 + sr) * K + sc;
  char* ldsA = (char*)(&As[0][0]) + (tid & ~63) * 16;
  char* ldsB = (char*)(&Bs[0][0]) + (tid & ~63) * 16;

#define STAGE_P(bsel, kofs)                                        \
  do {                                                             \
    GLOAD_LDS16(A + aBase0 + (kofs), ldsA + (bsel) * 8192);        \
    GLOAD_LDS16(A + aBase1 + (kofs), ldsA + (bsel) * 8192 + 4096); \
    GLOAD_LDS16(B + bBase0 + (kofs), ldsB + (bsel) * 8192);        \
    GLOAD_LDS16(B + bBase1 + (kofs), ldsB + (bsel) * 8192 + 4096); \
  } while (0)

  STAGE_P(0, 0);

  f32x4 acc[4][4];
  const f32x4 zero = {0.f, 0.f, 0.f, 0.f};
  #pragma unroll
  for (int i = 0; i < 4; ++i)
    #pragma unroll
    for (int j = 0; j < 4; ++j) acc[i][j] = zero;

  const int lr   = lane & 15;
  const int slot = (lane >> 4) ^ ((lr >> 1) & 3);

  auto compute = [&](const unsigned short* Asb, const unsigned short* Bsb) {
    half8v af[4], bfr[4];
    #pragma unroll
    for (int i = 0; i < 4; ++i)
      af[i] = *reinterpret_cast<const half8v*>(Asb + (wr * 64 + i * 16 + lr) * 32 + slot * 8);
    #pragma unroll
    for (int j = 0; j < 4; ++j)
      bfr[j] = *reinterpret_cast<const half8v*>(Bsb + (wc * 64 + j * 16 + lr) * 32 + slot * 8);
    __builtin_amdgcn_s_setprio(1);
    #pragma unroll
    for (int i = 0; i < 4; ++i)
      #pragma unroll
      for (int j = 0; j < 4; ++j)
        acc[i][j] = __builtin_amdgcn_mfma_f32_16x16x32_f16(bfr[j], af[i], acc[i][j], 0, 0, 0);
    __builtin_amdgcn_s_setprio(0);
  };

  const int nt = K >> 5;
  for (int t = 0; t < nt - 1; ++t) {
    STAGE_P((t + 1) & 1, (t + 1) * 32);
    asm volatile("s_waitcnt vmcnt(4)" ::: "memory");
    __builtin_amdgcn_s_barrier();
    __builtin_amdgcn_sched_barrier(0);
    compute(&As[t & 1][0], &Bs[t & 1][0]);
    __builtin_amdgcn_s_barrier();
    __builtin_amdgcn_sched_barrier(0);
  }
  asm volatile("s_waitcnt vmcnt(0)" ::: "memory");
  __builtin_amdgcn_s_barrier();
  __builtin_amdgcn_sched_barrier(0);
  compute(&As[(nt - 1) & 1][0], &Bs[(nt - 1) & 1][0]);
#undef STAGE_P

  const int cr = (lane >> 4) * 4;
  const int cc = lane & 15;
  #pragma unroll
  for (int j = 0; j < 4; ++j) {
    const int n = n0 + wc * 64 + j * 16 + cr;
    const float4 b4 = *reinterpret_cast<const float4*>(bias + n);
    #pragma unroll
    for (int i = 0; i < 4; ++i) {
      const int m = m0 + wr * 64 + i * 16 + cc;
      float4 r;
      r.x = acc[i][j][0] + b4.x;
      r.y = acc[i][j][1] + b4.y;
      r.z = acc[i][j][2] + b4.z;
      r.w = acc[i][j][3] + b4.w;
      *reinterpret_cast<float4*>(Cf + (size_t)m * N + n) = r;
    }
  }
}

// ---------- stripe attention + LePE, TWO windows per wave ----------
__global__ __launch_bounds__(256) void attn_lepe(
    const unsigned short* __restrict__ qkvp,
    const unsigned short* __restrict__ wlep,
    unsigned short* __restrict__ outp)
{
  const int gw   = (int)((blockIdx.x * 256 + threadIdx.x) >> 6);  // pair index
  const int lane = threadIdx.x & 63;
  const int half = gw >> 14;
  const int id   = gw & 16383;
  const int b    = id >> 11;
  const int n    = (id >> 8) & 7;
  int h0, w0;
  if (half == 0) { h0 = ((id >> 5) & 7) * 8; w0 = (id & 31) * 2; }
  else           { h0 = ((id >> 3) & 31) * 2; w0 = (id & 7) * 8; }
  const int baseA = qkv_idx(half, b, n, h0, w0);
  const int dWin  = (half == 0) ? 256 : 2048;
  const int baseB = baseA + dWin;

  // ---- QK^T for both windows: lane = (qr, kr) ----
  const int qr = lane >> 3, kr = lane & 7;
  const unsigned short* qA = qkvp + baseA + qr * 32;
  const unsigned short* kA = qkvp + 16777216 + baseA + kr * 32;
  float sA = 0.f, sB = 0.f;
  #pragma unroll
  for (int c = 0; c < 4; ++c) {
    const u32x4 qa = *reinterpret_cast<const u32x4*>(qA + c * 8);
    const u32x4 ka = *reinterpret_cast<const u32x4*>(kA + c * 8);
    const u32x4 qb = *reinterpret_cast<const u32x4*>(qA + dWin + c * 8);
    const u32x4 kb = *reinterpret_cast<const u32x4*>(kA + dWin + c * 8);
    #pragma unroll
    for (int e = 0; e < 4; ++e) {
      sA = __builtin_amdgcn_fdot2(bch2(qa[e]), bch2(ka[e]), sA, false);
      sB = __builtin_amdgcn_fdot2(bch2(qb[e]), bch2(kb[e]), sB, false);
    }
  }
  const float scl = 0.17677669529663687f;
  const float pA = __expf(sA * scl);
  const float pB = __expf(sB * scl);
  float denA = pA, denB = pB;
  denA += __shfl_xor(denA, 1); denA += __shfl_xor(denA, 2); denA += __shfl_xor(denA, 4);
  denB += __shfl_xor(denB, 1); denB += __shfl_xor(denB, 2); denB += __shfl_xor(denB, 4);
  const float aAv = pA * __builtin_amdgcn_rcpf(denA);
  const float aBv = pB * __builtin_amdgcn_rcpf(denB);
  const uint32_t adu = pkrtz_u32(aAv, aBv);   // lo = winA, hi = winB

  // ---- PV: lane = (qr2, win, dgrp); 16B vectors over 8 channels ----
  const int dgrp = lane & 3;
  const int win  = (lane >> 2) & 1;
  const int qr2  = lane >> 3;
  const int d0   = dgrp * 8;
  const int mybase = win ? baseB : baseA;
  const unsigned short* vwin = qkvp + 33554432 + mybase;

  half2v o01 = {0,0}, o23 = {0,0}, o45 = {0,0}, o67 = {0,0};
  #pragma unroll
  for (int k = 0; k < 8; ++k) {
    const uint32_t pairw = (uint32_t)__shfl((int)adu, qr2 * 8 + k);
    const half2v ph = bch2(pairw);
    const _Float16 av = win ? ph.y : ph.x;
    const half2v ak2 = {av, av};
    const u32x4 vv = *reinterpret_cast<const u32x4*>(vwin + k * 32 + d0);
    o01 += ak2 * bch2(vv[0]);
    o23 += ak2 * bch2(vv[1]);
    o45 += ak2 * bch2(vv[2]);
    o67 += ak2 * bch2(vv[3]);
  }

  // ---- LePE: depthwise 3x3 on v (zero-pad SAME) at this lane's pixel ----
  const int hq = (half == 0) ? (h0 + qr2) : (h0 + win);
  const int wq = (half == 0) ? (w0 + win) : (w0 + qr2);
  const unsigned short* vplane = qkvp + 33554432;
  const unsigned short* wl = wlep + half * 2304 + n * 32 + d0;
  half2v l01 = {0,0}, l23 = {0,0}, l45 = {0,0}, l67 = {0,0};
  #pragma unroll
  for (int dy = -1; dy <= 1; ++dy) {
    #pragma unroll
    for (int dx = -1; dx <= 1; ++dx) {
      const int hh = hq + dy, ww = wq + dx;
      u32x4 vv = {0u, 0u, 0u, 0u};
      if ((unsigned)hh < 64u && (unsigned)ww < 64u)
        vv = *reinterpret_cast<const u32x4*>(vplane + qkv_idx(half, b, n, hh, ww) + d0);
      const u32x4 wt = *reinterpret_cast<const u32x4*>(wl + ((dy + 1) * 3 + dx + 1) * 256);
      l01 += bch2(wt[0]) * bch2(vv[0]);
      l23 += bch2(wt[1]) * bch2(vv[1]);
      l45 += bch2(wt[2]) * bch2(vv[2]);
      l67 += bch2(wt[3]) * bch2(vv[3]);
    }
  }

  // ---- store token-major for GEMM2 (16B per lane) ----
  const int m = b * 4096 + hq * 64 + wq;
  const int chan0 = half * 256 + n * 32;
  u32x4 r;
  r[0] = __builtin_bit_cast(uint32_t, (half2v)(o01 + l01));
  r[1] = __builtin_bit_cast(uint32_t, (half2v)(o23 + l23));
  r[2] = __builtin_bit_cast(uint32_t, (half2v)(o45 + l45));
  r[3] = __builtin_bit_cast(uint32_t, (half2v)(o67 + l67));
  *reinterpret_cast<u32x4*>(outp + (size_t)m * 512 + chan0 + d0) = r;
}

// ---------- launch ----------
extern "C" void kernel_launch(void* const* d_in, const int* in_sizes, int n_in,
                              void* d_out, int out_size, void* d_ws, size_t ws_size,
                              hipStream_t stream) {
  const float* x      = (const float*)d_in[0];   // (8, 4096, 512)
  const float* w_qkv  = (const float*)d_in[1];   // (1536, 512)
  const float* w_proj = (const float*)d_in[2];   // (512, 512)
  const float* b_proj = (const float*)d_in[3];   // (512,)
  const float* lepe_h = (const float*)d_in[4];   // (3,3,1,256)
  const float* lepe_v = (const float*)d_in[5];   // (3,3,1,256)
  float* out = (float*)d_out;                    // (8, 4096, 512) f32

  char* ws = (char*)d_ws;
  unsigned short* qkv_p   = (unsigned short*)ws;                 // 96MB: q|k|v window-major
  unsigned short* xh      = (unsigned short*)(ws + 100663296);   // 32MB: x f16; reused as attn_out
  unsigned short* wqkv_h  = (unsigned short*)(ws + 134217728);   // 1536*512 f16
  unsigned short* wproj_h = (unsigned short*)(ws + 135790592);   // 512*512 f16
  unsigned short* wlep_h  = (unsigned short*)(ws + 136314880);   // 2*9*256 f16

  // all casts in one launch
  cvt_all<<<17413, 256, 0, stream>>>(x, w_qkv, w_proj, lepe_h, lepe_v,
                                     xh, wqkv_h, wproj_h, wlep_h);

  // qkv = x @ w_qkv^T -> window-major f16 (persistent 8-phase; 1 block/CU)
  gemm8p<<<256, 512, 0, stream>>>(xh, wqkv_h, qkv_p);

  // stripe attention + LePE -> attn_out token-major (xh dead -> reuse)
  attn_lepe<<<8192, 256, 0, stream>>>(qkv_p, wlep_h, xh);

  // out = attn_out @ w_proj^T + b_proj -> f32 (128^2 2-phase; grid 1024)
  gemm_proj<<<1024, 256, 0, stream>>>(xh, wproj_h, out, b_proj);
}